// Round 1
// baseline (1145.208 us; speedup 1.0000x reference)
//
#include <hip/hip_runtime.h>
#include <hip/hip_bf16.h>

#define N_NODES 50000
#define N_EDGES 800000
#define DIM     256
#define NLAYERS 4
#define EPS     1e-5f
#define SCAN_B  196   // ceil(50000/256)

typedef __bf16 bf16x8 __attribute__((ext_vector_type(8)));
typedef float  f32x4  __attribute__((ext_vector_type(4)));
typedef unsigned short u16x8 __attribute__((ext_vector_type(8)));

__device__ __forceinline__ unsigned short f2b(float f) {
    __hip_bfloat16 h = __float2bfloat16(f);
    return __builtin_bit_cast(unsigned short, h);
}
__device__ __forceinline__ float gelu_exact(float x) {
    return 0.5f * x * (1.0f + erff(x * 0.70710678118654752f));
}

// ---- setup kernels ------------------------------------------------------
__global__ __launch_bounds__(256) void init_kernel(float* deg, int* counts) {
    int i = blockIdx.x * 256 + threadIdx.x;
    if (i < N_NODES) { deg[i] = 1.0f; counts[i] = 0; }  // 1.0 = self-loop weight
}

__global__ __launch_bounds__(256) void hist_kernel(const int* __restrict__ dst,
                                                   const float* __restrict__ w,
                                                   float* deg, int* counts) {
    int e = blockIdx.x * 256 + threadIdx.x;
    if (e >= N_EDGES) return;
    int d = dst[e];
    atomicAdd(&deg[d], w[e]);
    atomicAdd(&counts[d], 1);
}

__global__ __launch_bounds__(256) void dinv_kernel(const float* __restrict__ deg,
                                                   float* __restrict__ dinv) {
    int i = blockIdx.x * 256 + threadIdx.x;
    if (i < N_NODES) dinv[i] = rsqrtf(deg[i]);  // deg >= 1 always (self-loop)
}

__global__ __launch_bounds__(256) void scan_a_kernel(const int* __restrict__ counts,
                                                     int* __restrict__ bsum) {
    __shared__ int l[256];
    int i = blockIdx.x * 256 + threadIdx.x;
    l[threadIdx.x] = (i < N_NODES) ? counts[i] : 0;
    __syncthreads();
    for (int o = 128; o > 0; o >>= 1) {
        if (threadIdx.x < o) l[threadIdx.x] += l[threadIdx.x + o];
        __syncthreads();
    }
    if (threadIdx.x == 0) bsum[blockIdx.x] = l[0];
}

__global__ __launch_bounds__(256) void scan_b_kernel(const int* __restrict__ bsum,
                                                     int* __restrict__ boff,
                                                     int* __restrict__ rowptr) {
    __shared__ int l[256];
    int t = threadIdx.x;
    l[t] = (t < SCAN_B) ? bsum[t] : 0;
    __syncthreads();
    if (t == 0) {
        int run = 0;
        for (int j = 0; j < SCAN_B; ++j) { int v = l[j]; l[j] = run; run += v; }
        rowptr[N_NODES] = run;  // == N_EDGES
    }
    __syncthreads();
    boff[t] = l[t];
}

__global__ __launch_bounds__(256) void scan_c_kernel(const int* __restrict__ counts,
                                                     const int* __restrict__ boff,
                                                     int* __restrict__ rowptr,
                                                     int* __restrict__ cursor) {
    __shared__ int l[256];
    int i = blockIdx.x * 256 + threadIdx.x;
    l[threadIdx.x] = (i < N_NODES) ? counts[i] : 0;
    __syncthreads();
    if (threadIdx.x == 0) {
        int run = 0;
        for (int j = 0; j < 256; ++j) { int v = l[j]; l[j] = run; run += v; }
    }
    __syncthreads();
    if (i < N_NODES) {
        int rp = boff[blockIdx.x] + l[threadIdx.x];
        rowptr[i] = rp;
        cursor[i] = rp;
    }
}

__global__ __launch_bounds__(256) void fill_kernel(const int* __restrict__ src,
                                                   const int* __restrict__ dst,
                                                   const float* __restrict__ w,
                                                   const float* __restrict__ dinv,
                                                   int* cursor, int2* __restrict__ epack) {
    int e = blockIdx.x * 256 + threadIdx.x;
    if (e >= N_EDGES) return;
    int s = src[e], d = dst[e];
    int p = atomicAdd(&cursor[d], 1);
    float c = dinv[s] * w[e] * dinv[d];
    epack[p] = make_int2(s, __float_as_int(c));
}

// conv_w[l][k][n] (l<4) and post_w[k][n] (slot 4) -> Wt[l][n][k] bf16
__global__ __launch_bounds__(256) void convw_kernel(const float* __restrict__ conv_w,
                                                    const float* __restrict__ post_w,
                                                    unsigned short* __restrict__ Wt) {
    int idx = blockIdx.x * 256 + threadIdx.x;
    if (idx >= 5 * 65536) return;
    int m = idx >> 16;
    int r = idx & 65535;
    int n = r >> 8;
    int k = r & 255;
    float v = (m < 4) ? conv_w[m * 65536 + k * 256 + n] : post_w[k * 256 + n];
    Wt[idx] = f2b(v);
}

// ---- per-layer kernels --------------------------------------------------
// wave-per-row LayerNorm (or plain cast when doLN==0) -> bf16
__global__ __launch_bounds__(256) void ln_cast_kernel(const float* __restrict__ H,
                                                      const float* __restrict__ lnw,
                                                      const float* __restrict__ lnb,
                                                      unsigned short* __restrict__ Z,
                                                      int doLN) {
    int row = blockIdx.x * 4 + (threadIdx.x >> 6);
    int lane = threadIdx.x & 63;
    const float4 x = *(const float4*)(H + (size_t)row * DIM + lane * 4);
    float y0 = x.x, y1 = x.y, y2 = x.z, y3 = x.w;
    if (doLN) {
        float s = x.x + x.y + x.z + x.w;
        for (int o = 32; o > 0; o >>= 1) s += __shfl_xor(s, o);
        float mu = s * (1.0f / DIM);
        float d0 = x.x - mu, d1 = x.y - mu, d2 = x.z - mu, d3 = x.w - mu;
        float v = d0 * d0 + d1 * d1 + d2 * d2 + d3 * d3;
        for (int o = 32; o > 0; o >>= 1) v += __shfl_xor(v, o);
        float rs = rsqrtf(v * (1.0f / DIM) + EPS);
        const float4 ww = *(const float4*)(lnw + lane * 4);
        const float4 bb = *(const float4*)(lnb + lane * 4);
        y0 = d0 * rs * ww.x + bb.x;
        y1 = d1 * rs * ww.y + bb.y;
        y2 = d2 * rs * ww.z + bb.z;
        y3 = d3 * rs * ww.w + bb.w;
    }
    ushort4 o4;
    o4.x = f2b(y0); o4.y = f2b(y1); o4.z = f2b(y2); o4.w = f2b(y3);
    *(ushort4*)(Z + (size_t)row * DIM + lane * 4) = o4;
}

// C[M x 256] = A_bf16[M x 256] @ Wt_bf16[n][k] (+ bias). Block = 4 waves;
// wave w does rows [16*bx,16*bx+16) x cols [64w, 64w+64) via 4 MFMA frags.
__global__ __launch_bounds__(256) void gemm_kernel(const unsigned short* __restrict__ A,
                                                   const unsigned short* __restrict__ Bt,
                                                   float* __restrict__ C,
                                                   const float* __restrict__ bias,
                                                   int hasBias) {
    int tid = threadIdx.x;
    int wave = tid >> 6;
    int lane = tid & 63;
    int q = lane >> 4;       // 0..3
    int c16 = lane & 15;     // 0..15
    int mbase = blockIdx.x * 16;
    int nbase = wave * 64;

    f32x4 acc[4] = {};
    const unsigned short* arow = A + (size_t)(mbase + c16) * DIM;
    #pragma unroll
    for (int k0 = 0; k0 < DIM; k0 += 32) {
        bf16x8 af = __builtin_bit_cast(bf16x8, *(const u16x8*)(arow + k0 + q * 8));
        #pragma unroll
        for (int t = 0; t < 4; ++t) {
            const unsigned short* bp = Bt + (size_t)(nbase + t * 16 + c16) * DIM + k0 + q * 8;
            bf16x8 bf = __builtin_bit_cast(bf16x8, *(const u16x8*)bp);
            acc[t] = __builtin_amdgcn_mfma_f32_16x16x32_bf16(af, bf, acc[t], 0, 0, 0);
        }
    }
    #pragma unroll
    for (int t = 0; t < 4; ++t) {
        int col = nbase + t * 16 + c16;
        float b = hasBias ? bias[col] : 0.0f;
        #pragma unroll
        for (int r = 0; r < 4; ++r) {
            int row = mbase + q * 4 + r;
            C[(size_t)row * DIM + col] = acc[t][r] + b;
        }
    }
}

// wave-per-node CSR aggregation + bias + exact GELU + residual
__global__ __launch_bounds__(256) void agg_kernel(const float* __restrict__ ZW,
                                                  const float* __restrict__ Hin,
                                                  float* __restrict__ Hout,
                                                  const float* __restrict__ bias,
                                                  const int* __restrict__ rowptr,
                                                  const int2* __restrict__ epack,
                                                  const float* __restrict__ dinv) {
    int node = blockIdx.x * 4 + (threadIdx.x >> 6);
    int lane = threadIdx.x & 63;
    float di = dinv[node];
    float sc = di * di;  // self-loop coef
    const float4 zself = *(const float4*)(ZW + (size_t)node * DIM + lane * 4);
    float a0 = sc * zself.x, a1 = sc * zself.y, a2 = sc * zself.z, a3 = sc * zself.w;
    int e0 = rowptr[node], e1 = rowptr[node + 1];
    for (int e = e0; e < e1; ++e) {
        int2 ep = epack[e];
        int s = ep.x;
        float c = __int_as_float(ep.y);
        const float4 v = *(const float4*)(ZW + (size_t)s * DIM + lane * 4);
        a0 += c * v.x; a1 += c * v.y; a2 += c * v.z; a3 += c * v.w;
    }
    const float4 bb = *(const float4*)(bias + lane * 4);
    const float4 hv = *(const float4*)(Hin + (size_t)node * DIM + lane * 4);
    float4 o;
    o.x = hv.x + gelu_exact(a0 + bb.x);
    o.y = hv.y + gelu_exact(a1 + bb.y);
    o.z = hv.z + gelu_exact(a2 + bb.z);
    o.w = hv.w + gelu_exact(a3 + bb.w);
    *(float4*)(Hout + (size_t)node * DIM + lane * 4) = o;
}

// ---- launch -------------------------------------------------------------
extern "C" void kernel_launch(void* const* d_in, const int* in_sizes, int n_in,
                              void* d_out, int out_size, void* d_ws, size_t ws_size,
                              hipStream_t stream) {
    const int*   ei     = (const int*)d_in[1];
    const int*   src    = ei;
    const int*   dst    = ei + N_EDGES;
    const float* ew     = (const float*)d_in[2];
    const float* emb    = (const float*)d_in[3];
    const float* ln_w   = (const float*)d_in[4];
    const float* ln_b   = (const float*)d_in[5];
    const float* conv_w = (const float*)d_in[6];
    const float* conv_b = (const float*)d_in[7];
    const float* post_w = (const float*)d_in[8];
    const float* post_b = (const float*)d_in[9];
    float* out = (float*)d_out;

    char* w = (char*)d_ws;
    size_t off = 0;
    auto alloc = [&](size_t bytes) -> char* {
        char* p = w + off;
        off += (bytes + 255) & ~(size_t)255;
        return p;
    };
    float* deg    = (float*)alloc((size_t)N_NODES * 4);
    float* dinv   = (float*)alloc((size_t)N_NODES * 4);
    int*   counts = (int*)alloc((size_t)N_NODES * 4);
    int*   rowptr = (int*)alloc((size_t)(N_NODES + 1) * 4);
    int*   cursor = (int*)alloc((size_t)N_NODES * 4);
    int*   bsum   = (int*)alloc(256 * 4);
    int*   boff   = (int*)alloc(256 * 4);
    int2*  epack  = (int2*)alloc((size_t)N_EDGES * 8);
    unsigned short* Wt  = (unsigned short*)alloc((size_t)5 * 65536 * 2);
    unsigned short* Z16 = (unsigned short*)alloc((size_t)N_NODES * DIM * 2);
    float* ZW = (float*)alloc((size_t)N_NODES * DIM * 4);
    float* H  = (float*)alloc((size_t)N_NODES * DIM * 4);
    // total ws use: ~136 MB

    init_kernel<<<SCAN_B, 256, 0, stream>>>(deg, counts);
    hist_kernel<<<N_EDGES / 256, 256, 0, stream>>>(dst, ew, deg, counts);
    dinv_kernel<<<SCAN_B, 256, 0, stream>>>(deg, dinv);
    scan_a_kernel<<<SCAN_B, 256, 0, stream>>>(counts, bsum);
    scan_b_kernel<<<1, 256, 0, stream>>>(bsum, boff, rowptr);
    scan_c_kernel<<<SCAN_B, 256, 0, stream>>>(counts, boff, rowptr, cursor);
    fill_kernel<<<N_EDGES / 256, 256, 0, stream>>>(src, dst, ew, dinv, cursor, epack);
    convw_kernel<<<(5 * 65536) / 256, 256, 0, stream>>>(conv_w, post_w, Wt);

    const float* hin = emb;
    for (int l = 0; l < NLAYERS; ++l) {
        ln_cast_kernel<<<N_NODES / 4, 256, 0, stream>>>(hin, ln_w + l * DIM, ln_b + l * DIM, Z16, 1);
        gemm_kernel<<<N_NODES / 16, 256, 0, stream>>>(Z16, Wt + (size_t)l * 65536, ZW, nullptr, 0);
        agg_kernel<<<N_NODES / 4, 256, 0, stream>>>(ZW, hin, H, conv_b + l * DIM, rowptr, epack, dinv);
        hin = H;
    }
    ln_cast_kernel<<<N_NODES / 4, 256, 0, stream>>>(H, nullptr, nullptr, Z16, 0);
    gemm_kernel<<<N_NODES / 16, 256, 0, stream>>>(Z16, Wt + (size_t)4 * 65536, out, post_b, 1);
}

// Round 2
// 972.710 us; speedup vs baseline: 1.1773x; 1.1773x over previous
//
#include <hip/hip_runtime.h>
#include <hip/hip_bf16.h>

#define N_NODES 50000
#define N_EDGES 800000
#define DIM     256
#define NLAYERS 4
#define EPS     1e-5f
#define SCAN_B  196   // ceil(50000/256)

typedef __bf16 bf16x8 __attribute__((ext_vector_type(8)));
typedef float  f32x4  __attribute__((ext_vector_type(4)));
typedef unsigned short u16x8 __attribute__((ext_vector_type(8)));

__device__ __forceinline__ unsigned short f2b(float f) {
    __hip_bfloat16 h = __float2bfloat16(f);
    return __builtin_bit_cast(unsigned short, h);
}
__device__ __forceinline__ float b2f(unsigned short u) {
    unsigned int v = ((unsigned int)u) << 16;
    return __builtin_bit_cast(float, v);
}
__device__ __forceinline__ float gelu_exact(float x) {
    return 0.5f * x * (1.0f + erff(x * 0.70710678118654752f));
}

// ---- setup kernels ------------------------------------------------------
__global__ __launch_bounds__(256) void init_kernel(float* deg, int* counts) {
    int i = blockIdx.x * 256 + threadIdx.x;
    if (i < N_NODES) { deg[i] = 1.0f; counts[i] = 0; }  // 1.0 = self-loop weight
}

__global__ __launch_bounds__(256) void hist_kernel(const int* __restrict__ dst,
                                                   const float* __restrict__ w,
                                                   float* deg, int* counts) {
    int e = blockIdx.x * 256 + threadIdx.x;
    if (e >= N_EDGES) return;
    int d = dst[e];
    atomicAdd(&deg[d], w[e]);
    atomicAdd(&counts[d], 1);
}

__global__ __launch_bounds__(256) void dinv_kernel(const float* __restrict__ deg,
                                                   float* __restrict__ dinv) {
    int i = blockIdx.x * 256 + threadIdx.x;
    if (i < N_NODES) dinv[i] = rsqrtf(deg[i]);  // deg >= 1 always (self-loop)
}

__global__ __launch_bounds__(256) void scan_a_kernel(const int* __restrict__ counts,
                                                     int* __restrict__ bsum) {
    __shared__ int l[256];
    int i = blockIdx.x * 256 + threadIdx.x;
    l[threadIdx.x] = (i < N_NODES) ? counts[i] : 0;
    __syncthreads();
    for (int o = 128; o > 0; o >>= 1) {
        if (threadIdx.x < o) l[threadIdx.x] += l[threadIdx.x + o];
        __syncthreads();
    }
    if (threadIdx.x == 0) bsum[blockIdx.x] = l[0];
}

__global__ __launch_bounds__(256) void scan_b_kernel(const int* __restrict__ bsum,
                                                     int* __restrict__ boff,
                                                     int* __restrict__ rowptr) {
    __shared__ int l[256];
    int t = threadIdx.x;
    l[t] = (t < SCAN_B) ? bsum[t] : 0;
    __syncthreads();
    if (t == 0) {
        int run = 0;
        for (int j = 0; j < SCAN_B; ++j) { int v = l[j]; l[j] = run; run += v; }
        rowptr[N_NODES] = run;  // == N_EDGES
    }
    __syncthreads();
    boff[t] = l[t];
}

__global__ __launch_bounds__(256) void scan_c_kernel(const int* __restrict__ counts,
                                                     const int* __restrict__ boff,
                                                     int* __restrict__ rowptr,
                                                     int* __restrict__ cursor) {
    __shared__ int l[256];
    int i = blockIdx.x * 256 + threadIdx.x;
    l[threadIdx.x] = (i < N_NODES) ? counts[i] : 0;
    __syncthreads();
    if (threadIdx.x == 0) {
        int run = 0;
        for (int j = 0; j < 256; ++j) { int v = l[j]; l[j] = run; run += v; }
    }
    __syncthreads();
    if (i < N_NODES) {
        int rp = boff[blockIdx.x] + l[threadIdx.x];
        rowptr[i] = rp;
        cursor[i] = rp;
    }
}

__global__ __launch_bounds__(256) void fill_kernel(const int* __restrict__ src,
                                                   const int* __restrict__ dst,
                                                   const float* __restrict__ w,
                                                   const float* __restrict__ dinv,
                                                   int* cursor, int2* __restrict__ epack) {
    int e = blockIdx.x * 256 + threadIdx.x;
    if (e >= N_EDGES) return;
    int s = src[e], d = dst[e];
    int p = atomicAdd(&cursor[d], 1);
    float c = dinv[s] * w[e] * dinv[d];
    epack[p] = make_int2(s, __float_as_int(c));
}

// conv_w[l][k][n] (l<4) and post_w[k][n] (slot 4) -> Wt[l][n][k] bf16
__global__ __launch_bounds__(256) void convw_kernel(const float* __restrict__ conv_w,
                                                    const float* __restrict__ post_w,
                                                    unsigned short* __restrict__ Wt) {
    int idx = blockIdx.x * 256 + threadIdx.x;
    if (idx >= 5 * 65536) return;
    int m = idx >> 16;
    int r = idx & 65535;
    int n = r >> 8;
    int k = r & 255;
    float v = (m < 4) ? conv_w[m * 65536 + k * 256 + n] : post_w[k * 256 + n];
    Wt[idx] = f2b(v);
}

// ---- per-layer kernels --------------------------------------------------
// wave-per-row LayerNorm + bf16 cast (used once, on emb)
__global__ __launch_bounds__(256) void ln_cast_kernel(const float* __restrict__ H,
                                                      const float* __restrict__ lnw,
                                                      const float* __restrict__ lnb,
                                                      unsigned short* __restrict__ Z) {
    int row = blockIdx.x * 4 + (threadIdx.x >> 6);
    int lane = threadIdx.x & 63;
    const float4 x = *(const float4*)(H + (size_t)row * DIM + lane * 4);
    float s = x.x + x.y + x.z + x.w;
    for (int o = 32; o > 0; o >>= 1) s += __shfl_xor(s, o);
    float mu = s * (1.0f / DIM);
    float d0 = x.x - mu, d1 = x.y - mu, d2 = x.z - mu, d3 = x.w - mu;
    float v = d0 * d0 + d1 * d1 + d2 * d2 + d3 * d3;
    for (int o = 32; o > 0; o >>= 1) v += __shfl_xor(v, o);
    float rs = rsqrtf(v * (1.0f / DIM) + EPS);
    const float4 ww = *(const float4*)(lnw + lane * 4);
    const float4 bb = *(const float4*)(lnb + lane * 4);
    ushort4 o4;
    o4.x = f2b(d0 * rs * ww.x + bb.x);
    o4.y = f2b(d1 * rs * ww.y + bb.y);
    o4.z = f2b(d2 * rs * ww.z + bb.z);
    o4.w = f2b(d3 * rs * ww.w + bb.w);
    *(ushort4*)(Z + (size_t)row * DIM + lane * 4) = o4;
}

// C = A_bf16[M x 256] @ Wt_bf16[n][k]; bf16 output (no bias — bias fused in agg)
__global__ __launch_bounds__(256) void gemm_bf16_kernel(const unsigned short* __restrict__ A,
                                                        const unsigned short* __restrict__ Bt,
                                                        unsigned short* __restrict__ C) {
    int tid = threadIdx.x;
    int wave = tid >> 6;
    int lane = tid & 63;
    int q = lane >> 4;
    int c16 = lane & 15;
    int mbase = blockIdx.x * 16;
    int nbase = wave * 64;

    f32x4 acc[4] = {};
    const unsigned short* arow = A + (size_t)(mbase + c16) * DIM;
    #pragma unroll
    for (int k0 = 0; k0 < DIM; k0 += 32) {
        bf16x8 af = __builtin_bit_cast(bf16x8, *(const u16x8*)(arow + k0 + q * 8));
        #pragma unroll
        for (int t = 0; t < 4; ++t) {
            const unsigned short* bp = Bt + (size_t)(nbase + t * 16 + c16) * DIM + k0 + q * 8;
            bf16x8 bf = __builtin_bit_cast(bf16x8, *(const u16x8*)bp);
            acc[t] = __builtin_amdgcn_mfma_f32_16x16x32_bf16(af, bf, acc[t], 0, 0, 0);
        }
    }
    #pragma unroll
    for (int t = 0; t < 4; ++t) {
        int col = nbase + t * 16 + c16;
        #pragma unroll
        for (int r = 0; r < 4; ++r) {
            int row = mbase + q * 4 + r;
            C[(size_t)row * DIM + col] = f2b(acc[t][r]);
        }
    }
}

// fp32 output + bias (final projection)
__global__ __launch_bounds__(256) void gemm_f32_kernel(const unsigned short* __restrict__ A,
                                                       const unsigned short* __restrict__ Bt,
                                                       float* __restrict__ C,
                                                       const float* __restrict__ bias) {
    int tid = threadIdx.x;
    int wave = tid >> 6;
    int lane = tid & 63;
    int q = lane >> 4;
    int c16 = lane & 15;
    int mbase = blockIdx.x * 16;
    int nbase = wave * 64;

    f32x4 acc[4] = {};
    const unsigned short* arow = A + (size_t)(mbase + c16) * DIM;
    #pragma unroll
    for (int k0 = 0; k0 < DIM; k0 += 32) {
        bf16x8 af = __builtin_bit_cast(bf16x8, *(const u16x8*)(arow + k0 + q * 8));
        #pragma unroll
        for (int t = 0; t < 4; ++t) {
            const unsigned short* bp = Bt + (size_t)(nbase + t * 16 + c16) * DIM + k0 + q * 8;
            bf16x8 bf = __builtin_bit_cast(bf16x8, *(const u16x8*)bp);
            acc[t] = __builtin_amdgcn_mfma_f32_16x16x32_bf16(af, bf, acc[t], 0, 0, 0);
        }
    }
    #pragma unroll
    for (int t = 0; t < 4; ++t) {
        int col = nbase + t * 16 + c16;
        float b = bias[col];
        #pragma unroll
        for (int r = 0; r < 4; ++r) {
            int row = mbase + q * 4 + r;
            C[(size_t)row * DIM + col] = acc[t][r] + b;
        }
    }
}

// wave-per-node CSR aggregation (bf16 gather) + bias + exact GELU + residual,
// fused with the NEXT stage's LayerNorm (or plain cast) -> Z16 bf16.
// doLN: 1 = LN with lnw/lnb, 0 = plain cast.  writeH: write fp32 Hout.
__global__ __launch_bounds__(256) void agg_kernel(const unsigned short* __restrict__ ZW,
                                                  const float* __restrict__ Hin,
                                                  float* __restrict__ Hout,
                                                  const float* __restrict__ bias,
                                                  const int* __restrict__ rowptr,
                                                  const int2* __restrict__ epack,
                                                  const float* __restrict__ dinv,
                                                  const float* __restrict__ lnw,
                                                  const float* __restrict__ lnb,
                                                  unsigned short* __restrict__ Zout,
                                                  int doLN, int writeH) {
    int node = blockIdx.x * 4 + (threadIdx.x >> 6);
    int lane = threadIdx.x & 63;
    float di = dinv[node];
    float sc = di * di;  // self-loop coef
    const ushort4 zs = *(const ushort4*)(ZW + (size_t)node * DIM + lane * 4);
    float a0 = sc * b2f(zs.x), a1 = sc * b2f(zs.y);
    float a2 = sc * b2f(zs.z), a3 = sc * b2f(zs.w);
    int e0 = rowptr[node], e1 = rowptr[node + 1];
    for (int e = e0; e < e1; ++e) {
        int2 ep = epack[e];
        int s = ep.x;
        float c = __int_as_float(ep.y);
        const ushort4 v = *(const ushort4*)(ZW + (size_t)s * DIM + lane * 4);
        a0 += c * b2f(v.x); a1 += c * b2f(v.y);
        a2 += c * b2f(v.z); a3 += c * b2f(v.w);
    }
    const float4 bb = *(const float4*)(bias + lane * 4);
    const float4 hv = *(const float4*)(Hin + (size_t)node * DIM + lane * 4);
    float o0 = hv.x + gelu_exact(a0 + bb.x);
    float o1 = hv.y + gelu_exact(a1 + bb.y);
    float o2 = hv.z + gelu_exact(a2 + bb.z);
    float o3 = hv.w + gelu_exact(a3 + bb.w);
    if (writeH) {
        float4 o; o.x = o0; o.y = o1; o.z = o2; o.w = o3;
        *(float4*)(Hout + (size_t)node * DIM + lane * 4) = o;
    }
    float y0 = o0, y1 = o1, y2 = o2, y3 = o3;
    if (doLN) {
        float s = o0 + o1 + o2 + o3;
        for (int o = 32; o > 0; o >>= 1) s += __shfl_xor(s, o);
        float mu = s * (1.0f / DIM);
        float d0 = o0 - mu, d1 = o1 - mu, d2 = o2 - mu, d3 = o3 - mu;
        float v = d0 * d0 + d1 * d1 + d2 * d2 + d3 * d3;
        for (int o = 32; o > 0; o >>= 1) v += __shfl_xor(v, o);
        float rs = rsqrtf(v * (1.0f / DIM) + EPS);
        const float4 ww = *(const float4*)(lnw + lane * 4);
        const float4 lb = *(const float4*)(lnb + lane * 4);
        y0 = d0 * rs * ww.x + lb.x;
        y1 = d1 * rs * ww.y + lb.y;
        y2 = d2 * rs * ww.z + lb.z;
        y3 = d3 * rs * ww.w + lb.w;
    }
    ushort4 o4;
    o4.x = f2b(y0); o4.y = f2b(y1); o4.z = f2b(y2); o4.w = f2b(y3);
    *(ushort4*)(Zout + (size_t)node * DIM + lane * 4) = o4;
}

// ---- launch -------------------------------------------------------------
extern "C" void kernel_launch(void* const* d_in, const int* in_sizes, int n_in,
                              void* d_out, int out_size, void* d_ws, size_t ws_size,
                              hipStream_t stream) {
    const int*   ei     = (const int*)d_in[1];
    const int*   src    = ei;
    const int*   dst    = ei + N_EDGES;
    const float* ew     = (const float*)d_in[2];
    const float* emb    = (const float*)d_in[3];
    const float* ln_w   = (const float*)d_in[4];
    const float* ln_b   = (const float*)d_in[5];
    const float* conv_w = (const float*)d_in[6];
    const float* conv_b = (const float*)d_in[7];
    const float* post_w = (const float*)d_in[8];
    const float* post_b = (const float*)d_in[9];
    float* out = (float*)d_out;

    char* w = (char*)d_ws;
    size_t off = 0;
    auto alloc = [&](size_t bytes) -> char* {
        char* p = w + off;
        off += (bytes + 255) & ~(size_t)255;
        return p;
    };
    float* deg    = (float*)alloc((size_t)N_NODES * 4);
    float* dinv   = (float*)alloc((size_t)N_NODES * 4);
    int*   counts = (int*)alloc((size_t)N_NODES * 4);
    int*   rowptr = (int*)alloc((size_t)(N_NODES + 1) * 4);
    int*   cursor = (int*)alloc((size_t)N_NODES * 4);
    int*   bsum   = (int*)alloc(256 * 4);
    int*   boff   = (int*)alloc(256 * 4);
    int2*  epack  = (int2*)alloc((size_t)N_EDGES * 8);
    unsigned short* Wt  = (unsigned short*)alloc((size_t)5 * 65536 * 2);
    unsigned short* Z16 = (unsigned short*)alloc((size_t)N_NODES * DIM * 2);
    unsigned short* ZWb = (unsigned short*)alloc((size_t)N_NODES * DIM * 2);
    float* H  = (float*)alloc((size_t)N_NODES * DIM * 4);

    init_kernel<<<SCAN_B, 256, 0, stream>>>(deg, counts);
    hist_kernel<<<N_EDGES / 256, 256, 0, stream>>>(dst, ew, deg, counts);
    dinv_kernel<<<SCAN_B, 256, 0, stream>>>(deg, dinv);
    scan_a_kernel<<<SCAN_B, 256, 0, stream>>>(counts, bsum);
    scan_b_kernel<<<1, 256, 0, stream>>>(bsum, boff, rowptr);
    scan_c_kernel<<<SCAN_B, 256, 0, stream>>>(counts, boff, rowptr, cursor);
    fill_kernel<<<N_EDGES / 256, 256, 0, stream>>>(src, dst, ew, dinv, cursor, epack);
    convw_kernel<<<(5 * 65536) / 256, 256, 0, stream>>>(conv_w, post_w, Wt);

    // layer 0 input: LN(emb) -> bf16
    ln_cast_kernel<<<N_NODES / 4, 256, 0, stream>>>(emb, ln_w, ln_b, Z16);
    const float* hin = emb;
    for (int l = 0; l < NLAYERS; ++l) {
        gemm_bf16_kernel<<<N_NODES / 16, 256, 0, stream>>>(Z16, Wt + (size_t)l * 65536, ZWb);
        int doLN = (l < NLAYERS - 1) ? 1 : 0;
        int writeH = (l < NLAYERS - 1) ? 1 : 0;
        const float* nlw = doLN ? (ln_w + (l + 1) * DIM) : nullptr;
        const float* nlb = doLN ? (ln_b + (l + 1) * DIM) : nullptr;
        agg_kernel<<<N_NODES / 4, 256, 0, stream>>>(ZWb, hin, H, conv_b + l * DIM,
                                                    rowptr, epack, dinv, nlw, nlb,
                                                    Z16, doLN, writeH);
        hin = H;
    }
    gemm_f32_kernel<<<N_NODES / 16, 256, 0, stream>>>(Z16, Wt + (size_t)4 * 65536, out, post_b);
}

// Round 3
// 744.626 us; speedup vs baseline: 1.5380x; 1.3063x over previous
//
#include <hip/hip_runtime.h>
#include <hip/hip_bf16.h>

#define N_NODES 50000
#define N_EDGES 800000
#define DIM     256
#define NLAYERS 4
#define EPS     1e-5f
#define SCAN_B  196   // ceil(50000/256)

typedef __bf16 bf16x8 __attribute__((ext_vector_type(8)));
typedef float  f32x4  __attribute__((ext_vector_type(4)));
typedef unsigned short u16x8 __attribute__((ext_vector_type(8)));

__device__ __forceinline__ unsigned short f2b(float f) {
    __hip_bfloat16 h = __float2bfloat16(f);
    return __builtin_bit_cast(unsigned short, h);
}
__device__ __forceinline__ float b2f(unsigned short u) {
    unsigned int v = ((unsigned int)u) << 16;
    return __builtin_bit_cast(float, v);
}
__device__ __forceinline__ float gelu_exact(float x) {
    return 0.5f * x * (1.0f + erff(x * 0.70710678118654752f));
}

// ---- setup kernels ------------------------------------------------------
__global__ __launch_bounds__(256) void init_kernel(float* deg, int* counts) {
    int i = blockIdx.x * 256 + threadIdx.x;
    if (i < N_NODES) { deg[i] = 1.0f; counts[i] = 0; }  // 1.0 = self-loop weight
}

__global__ __launch_bounds__(256) void hist_kernel(const int* __restrict__ dst,
                                                   const float* __restrict__ w,
                                                   float* deg, int* counts) {
    int e = blockIdx.x * 256 + threadIdx.x;
    if (e >= N_EDGES) return;
    int d = dst[e];
    atomicAdd(&deg[d], w[e]);
    atomicAdd(&counts[d], 1);
}

__global__ __launch_bounds__(256) void dinv_kernel(const float* __restrict__ deg,
                                                   float* __restrict__ dinv) {
    int i = blockIdx.x * 256 + threadIdx.x;
    if (i < N_NODES) dinv[i] = rsqrtf(deg[i]);  // deg >= 1 always (self-loop)
}

__global__ __launch_bounds__(256) void scan_a_kernel(const int* __restrict__ counts,
                                                     int* __restrict__ bsum) {
    __shared__ int l[256];
    int i = blockIdx.x * 256 + threadIdx.x;
    l[threadIdx.x] = (i < N_NODES) ? counts[i] : 0;
    __syncthreads();
    for (int o = 128; o > 0; o >>= 1) {
        if (threadIdx.x < o) l[threadIdx.x] += l[threadIdx.x + o];
        __syncthreads();
    }
    if (threadIdx.x == 0) bsum[blockIdx.x] = l[0];
}

__global__ __launch_bounds__(256) void scan_b_kernel(const int* __restrict__ bsum,
                                                     int* __restrict__ boff,
                                                     int* __restrict__ rowptr) {
    __shared__ int l[256];
    int t = threadIdx.x;
    l[t] = (t < SCAN_B) ? bsum[t] : 0;
    __syncthreads();
    if (t == 0) {
        int run = 0;
        for (int j = 0; j < SCAN_B; ++j) { int v = l[j]; l[j] = run; run += v; }
        rowptr[N_NODES] = run;  // == N_EDGES
    }
    __syncthreads();
    boff[t] = l[t];
}

__global__ __launch_bounds__(256) void scan_c_kernel(const int* __restrict__ counts,
                                                     const int* __restrict__ boff,
                                                     int* __restrict__ rowptr,
                                                     int* __restrict__ cursor) {
    __shared__ int l[256];
    int i = blockIdx.x * 256 + threadIdx.x;
    l[threadIdx.x] = (i < N_NODES) ? counts[i] : 0;
    __syncthreads();
    if (threadIdx.x == 0) {
        int run = 0;
        for (int j = 0; j < 256; ++j) { int v = l[j]; l[j] = run; run += v; }
    }
    __syncthreads();
    if (i < N_NODES) {
        int rp = boff[blockIdx.x] + l[threadIdx.x];
        rowptr[i] = rp;
        cursor[i] = rp;
    }
}

__global__ __launch_bounds__(256) void fill_kernel(const int* __restrict__ src,
                                                   const int* __restrict__ dst,
                                                   const float* __restrict__ w,
                                                   const float* __restrict__ dinv,
                                                   int* cursor, int2* __restrict__ epack) {
    int e = blockIdx.x * 256 + threadIdx.x;
    if (e >= N_EDGES) return;
    int s = src[e], d = dst[e];
    int p = atomicAdd(&cursor[d], 1);
    float c = dinv[s] * w[e] * dinv[d];
    epack[p] = make_int2(s, __float_as_int(c));
}

// conv_w[l][k][n] (l<4) and post_w[k][n] (slot 4) -> Wt[l][n][k] bf16
__global__ __launch_bounds__(256) void convw_kernel(const float* __restrict__ conv_w,
                                                    const float* __restrict__ post_w,
                                                    unsigned short* __restrict__ Wt) {
    int idx = blockIdx.x * 256 + threadIdx.x;
    if (idx >= 5 * 65536) return;
    int m = idx >> 16;
    int r = idx & 65535;
    int n = r >> 8;
    int k = r & 255;
    float v = (m < 4) ? conv_w[m * 65536 + k * 256 + n] : post_w[k * 256 + n];
    Wt[idx] = f2b(v);
}

// ---- per-layer kernels --------------------------------------------------
// wave-per-row LayerNorm + bf16 cast (used once, on emb)
__global__ __launch_bounds__(256) void ln_cast_kernel(const float* __restrict__ H,
                                                      const float* __restrict__ lnw,
                                                      const float* __restrict__ lnb,
                                                      unsigned short* __restrict__ Z) {
    int row = blockIdx.x * 4 + (threadIdx.x >> 6);
    int lane = threadIdx.x & 63;
    const float4 x = *(const float4*)(H + (size_t)row * DIM + lane * 4);
    float s = x.x + x.y + x.z + x.w;
    for (int o = 32; o > 0; o >>= 1) s += __shfl_xor(s, o);
    float mu = s * (1.0f / DIM);
    float d0 = x.x - mu, d1 = x.y - mu, d2 = x.z - mu, d3 = x.w - mu;
    float v = d0 * d0 + d1 * d1 + d2 * d2 + d3 * d3;
    for (int o = 32; o > 0; o >>= 1) v += __shfl_xor(v, o);
    float rs = rsqrtf(v * (1.0f / DIM) + EPS);
    const float4 ww = *(const float4*)(lnw + lane * 4);
    const float4 bb = *(const float4*)(lnb + lane * 4);
    ushort4 o4;
    o4.x = f2b(d0 * rs * ww.x + bb.x);
    o4.y = f2b(d1 * rs * ww.y + bb.y);
    o4.z = f2b(d2 * rs * ww.z + bb.z);
    o4.w = f2b(d3 * rs * ww.w + bb.w);
    *(ushort4*)(Z + (size_t)row * DIM + lane * 4) = o4;
}

// ---- GEMM: block = 4 waves, tile 64 rows x 256 cols; wave w: 64 rows x cols
// [64w,64w+64). 16 MFMA per k-step. LDS-transpose epilogue -> 16B stores.
// MODE 0: bf16 out, no bias.  MODE 1: fp32 out + bias.
template <int MODE>
__device__ __forceinline__ void gemm_body(const unsigned short* __restrict__ A,
                                          const unsigned short* __restrict__ Bt,
                                          void* __restrict__ Cout,
                                          const float* __restrict__ bias) {
    __shared__ float lds[4 * 16 * 68];   // per-wave 16x68 fp32 (pad 4 vs 64)
    int tid = threadIdx.x;
    int wave = tid >> 6;
    int lane = tid & 63;
    int q = lane >> 4;
    int c16 = lane & 15;
    int mbase = blockIdx.x * 64;
    int nbase = wave * 64;

    f32x4 acc[4][4] = {};
    const unsigned short* ap[4];
    #pragma unroll
    for (int mt = 0; mt < 4; ++mt) {
        int row = mbase + mt * 16 + c16;
        if (row >= N_NODES) row = N_NODES - 1;   // clamp (stores guarded)
        ap[mt] = A + (size_t)row * DIM;
    }
    #pragma unroll
    for (int k0 = 0; k0 < DIM; k0 += 32) {
        bf16x8 af[4], bf[4];
        #pragma unroll
        for (int mt = 0; mt < 4; ++mt)
            af[mt] = __builtin_bit_cast(bf16x8, *(const u16x8*)(ap[mt] + k0 + q * 8));
        #pragma unroll
        for (int t = 0; t < 4; ++t)
            bf[t] = __builtin_bit_cast(bf16x8,
                *(const u16x8*)(Bt + (size_t)(nbase + t * 16 + c16) * DIM + k0 + q * 8));
        #pragma unroll
        for (int mt = 0; mt < 4; ++mt)
            #pragma unroll
            for (int t = 0; t < 4; ++t)
                acc[mt][t] = __builtin_amdgcn_mfma_f32_16x16x32_bf16(af[mt], bf[t], acc[mt][t], 0, 0, 0);
    }

    // epilogue: per m-subtile, stage in LDS (per-wave buffer, no barrier needed)
    float* wl = lds + wave * 16 * 68;
    int orow = lane >> 2;            // 0..15
    int cg = (lane & 3) * 16;        // 0,16,32,48
    float4 bb0, bb1, bb2, bb3;
    if (MODE == 1) {
        bb0 = *(const float4*)(bias + nbase + cg);
        bb1 = *(const float4*)(bias + nbase + cg + 4);
        bb2 = *(const float4*)(bias + nbase + cg + 8);
        bb3 = *(const float4*)(bias + nbase + cg + 12);
    }
    #pragma unroll
    for (int mt = 0; mt < 4; ++mt) {
        #pragma unroll
        for (int t = 0; t < 4; ++t)
            #pragma unroll
            for (int r = 0; r < 4; ++r)
                wl[(q * 4 + r) * 68 + t * 16 + c16] = acc[mt][t][r];
        __builtin_amdgcn_s_waitcnt(0);   // lgkm drain; same-wave LDS RAW
        int grow = mbase + mt * 16 + orow;
        if (grow < N_NODES) {
            const float4 v0 = *(const float4*)(wl + orow * 68 + cg);
            const float4 v1 = *(const float4*)(wl + orow * 68 + cg + 4);
            const float4 v2 = *(const float4*)(wl + orow * 68 + cg + 8);
            const float4 v3 = *(const float4*)(wl + orow * 68 + cg + 12);
            if (MODE == 0) {
                unsigned short* C = (unsigned short*)Cout;
                u16x8 lo, hi;
                lo[0] = f2b(v0.x); lo[1] = f2b(v0.y); lo[2] = f2b(v0.z); lo[3] = f2b(v0.w);
                lo[4] = f2b(v1.x); lo[5] = f2b(v1.y); lo[6] = f2b(v1.z); lo[7] = f2b(v1.w);
                hi[0] = f2b(v2.x); hi[1] = f2b(v2.y); hi[2] = f2b(v2.z); hi[3] = f2b(v2.w);
                hi[4] = f2b(v3.x); hi[5] = f2b(v3.y); hi[6] = f2b(v3.z); hi[7] = f2b(v3.w);
                size_t base = (size_t)grow * DIM + nbase + cg;
                *(u16x8*)(C + base) = lo;
                *(u16x8*)(C + base + 8) = hi;
            } else {
                float* C = (float*)Cout;
                size_t base = (size_t)grow * DIM + nbase + cg;
                float4 o0, o1, o2, o3;
                o0.x = v0.x + bb0.x; o0.y = v0.y + bb0.y; o0.z = v0.z + bb0.z; o0.w = v0.w + bb0.w;
                o1.x = v1.x + bb1.x; o1.y = v1.y + bb1.y; o1.z = v1.z + bb1.z; o1.w = v1.w + bb1.w;
                o2.x = v2.x + bb2.x; o2.y = v2.y + bb2.y; o2.z = v2.z + bb2.z; o2.w = v2.w + bb2.w;
                o3.x = v3.x + bb3.x; o3.y = v3.y + bb3.y; o3.z = v3.z + bb3.z; o3.w = v3.w + bb3.w;
                *(float4*)(C + base) = o0;
                *(float4*)(C + base + 4) = o1;
                *(float4*)(C + base + 8) = o2;
                *(float4*)(C + base + 12) = o3;
            }
        }
        __builtin_amdgcn_s_waitcnt(0);   // before next mt overwrites LDS
    }
}

__global__ __launch_bounds__(256) void gemm_bf16_kernel(const unsigned short* __restrict__ A,
                                                        const unsigned short* __restrict__ Bt,
                                                        unsigned short* __restrict__ C) {
    gemm_body<0>(A, Bt, C, nullptr);
}

__global__ __launch_bounds__(256) void gemm_f32_kernel(const unsigned short* __restrict__ A,
                                                       const unsigned short* __restrict__ Bt,
                                                       float* __restrict__ C,
                                                       const float* __restrict__ bias) {
    gemm_body<1>(A, Bt, C, bias);
}

// wave-per-node CSR aggregation: half-wave (32 lanes x 16B) per edge-row,
// 2 pairs unrolled -> 4 row-gathers in flight per wave. Fused bias + exact
// GELU + residual + next-layer LN/cast -> Z16 bf16.
__global__ __launch_bounds__(256) void agg_kernel(const unsigned short* __restrict__ ZW,
                                                  const float* __restrict__ Hin,
                                                  float* __restrict__ Hout,
                                                  const float* __restrict__ bias,
                                                  const int* __restrict__ rowptr,
                                                  const int2* __restrict__ epack,
                                                  const float* __restrict__ dinv,
                                                  const float* __restrict__ lnw,
                                                  const float* __restrict__ lnb,
                                                  unsigned short* __restrict__ Zout,
                                                  int doLN, int writeH) {
    int node = blockIdx.x * 4 + (threadIdx.x >> 6);
    int lane = threadIdx.x & 63;
    int g = lane >> 5;          // half id: which edge of a pair
    int col0 = (lane & 31) * 8; // 8 contiguous cols per lane

    float di = dinv[node];
    float scg = (g == 0) ? di * di : 0.0f;   // self-loop only in half 0
    const u16x8 zs = *(const u16x8*)(ZW + (size_t)node * DIM + col0);
    float a[8];
    #pragma unroll
    for (int j = 0; j < 8; ++j) a[j] = scg * b2f(zs[j]);

    int e0 = rowptr[node], e1 = rowptr[node + 1];
    for (int e = e0; e < e1; e += 4) {
        int i0 = e + g;
        int i1 = e + 2 + g;
        int2 ep0 = (i0 < e1) ? epack[i0] : make_int2(0, 0);
        int2 ep1 = (i1 < e1) ? epack[i1] : make_int2(0, 0);
        const u16x8 v0 = *(const u16x8*)(ZW + (size_t)ep0.x * DIM + col0);
        const u16x8 v1 = *(const u16x8*)(ZW + (size_t)ep1.x * DIM + col0);
        float c0 = __int_as_float(ep0.y);
        float c1 = __int_as_float(ep1.y);
        #pragma unroll
        for (int j = 0; j < 8; ++j) {
            a[j] += c0 * b2f(v0[j]);
            a[j] += c1 * b2f(v1[j]);
        }
    }
    // combine the two halves
    #pragma unroll
    for (int j = 0; j < 8; ++j) a[j] += __shfl_xor(a[j], 32);

    const float4 bb0 = *(const float4*)(bias + col0);
    const float4 bb1 = *(const float4*)(bias + col0 + 4);
    const float4 h0 = *(const float4*)(Hin + (size_t)node * DIM + col0);
    const float4 h1 = *(const float4*)(Hin + (size_t)node * DIM + col0 + 4);
    float o[8];
    o[0] = h0.x + gelu_exact(a[0] + bb0.x);
    o[1] = h0.y + gelu_exact(a[1] + bb0.y);
    o[2] = h0.z + gelu_exact(a[2] + bb0.z);
    o[3] = h0.w + gelu_exact(a[3] + bb0.w);
    o[4] = h1.x + gelu_exact(a[4] + bb1.x);
    o[5] = h1.y + gelu_exact(a[5] + bb1.y);
    o[6] = h1.z + gelu_exact(a[6] + bb1.z);
    o[7] = h1.w + gelu_exact(a[7] + bb1.w);

    if (writeH && g == 0) {
        float4 w0, w1;
        w0.x = o[0]; w0.y = o[1]; w0.z = o[2]; w0.w = o[3];
        w1.x = o[4]; w1.y = o[5]; w1.z = o[6]; w1.w = o[7];
        *(float4*)(Hout + (size_t)node * DIM + col0) = w0;
        *(float4*)(Hout + (size_t)node * DIM + col0 + 4) = w1;
    }

    float y[8];
    #pragma unroll
    for (int j = 0; j < 8; ++j) y[j] = o[j];
    if (doLN) {
        float s = 0.0f;
        #pragma unroll
        for (int j = 0; j < 8; ++j) s += o[j];
        for (int off = 16; off > 0; off >>= 1) s += __shfl_xor(s, off);
        float mu = s * (1.0f / DIM);
        float v = 0.0f;
        float d[8];
        #pragma unroll
        for (int j = 0; j < 8; ++j) { d[j] = o[j] - mu; v += d[j] * d[j]; }
        for (int off = 16; off > 0; off >>= 1) v += __shfl_xor(v, off);
        float rs = rsqrtf(v * (1.0f / DIM) + EPS);
        const float4 ww0 = *(const float4*)(lnw + col0);
        const float4 ww1 = *(const float4*)(lnw + col0 + 4);
        const float4 lb0 = *(const float4*)(lnb + col0);
        const float4 lb1 = *(const float4*)(lnb + col0 + 4);
        y[0] = d[0] * rs * ww0.x + lb0.x;
        y[1] = d[1] * rs * ww0.y + lb0.y;
        y[2] = d[2] * rs * ww0.z + lb0.z;
        y[3] = d[3] * rs * ww0.w + lb0.w;
        y[4] = d[4] * rs * ww1.x + lb1.x;
        y[5] = d[5] * rs * ww1.y + lb1.y;
        y[6] = d[6] * rs * ww1.z + lb1.z;
        y[7] = d[7] * rs * ww1.w + lb1.w;
    }
    if (g == 0) {
        u16x8 z;
        #pragma unroll
        for (int j = 0; j < 8; ++j) z[j] = f2b(y[j]);
        *(u16x8*)(Zout + (size_t)node * DIM + col0) = z;
    }
}

// ---- launch -------------------------------------------------------------
extern "C" void kernel_launch(void* const* d_in, const int* in_sizes, int n_in,
                              void* d_out, int out_size, void* d_ws, size_t ws_size,
                              hipStream_t stream) {
    const int*   ei     = (const int*)d_in[1];
    const int*   src    = ei;
    const int*   dst    = ei + N_EDGES;
    const float* ew     = (const float*)d_in[2];
    const float* emb    = (const float*)d_in[3];
    const float* ln_w   = (const float*)d_in[4];
    const float* ln_b   = (const float*)d_in[5];
    const float* conv_w = (const float*)d_in[6];
    const float* conv_b = (const float*)d_in[7];
    const float* post_w = (const float*)d_in[8];
    const float* post_b = (const float*)d_in[9];
    float* out = (float*)d_out;

    char* w = (char*)d_ws;
    size_t off = 0;
    auto alloc = [&](size_t bytes) -> char* {
        char* p = w + off;
        off += (bytes + 255) & ~(size_t)255;
        return p;
    };
    float* deg    = (float*)alloc((size_t)N_NODES * 4);
    float* dinv   = (float*)alloc((size_t)N_NODES * 4);
    int*   counts = (int*)alloc((size_t)N_NODES * 4);
    int*   rowptr = (int*)alloc((size_t)(N_NODES + 1) * 4);
    int*   cursor = (int*)alloc((size_t)N_NODES * 4);
    int*   bsum   = (int*)alloc(256 * 4);
    int*   boff   = (int*)alloc(256 * 4);
    int2*  epack  = (int2*)alloc((size_t)N_EDGES * 8);
    unsigned short* Wt  = (unsigned short*)alloc((size_t)5 * 65536 * 2);
    unsigned short* Z16 = (unsigned short*)alloc((size_t)N_NODES * DIM * 2);
    unsigned short* ZWb = (unsigned short*)alloc((size_t)N_NODES * DIM * 2);
    float* H  = (float*)alloc((size_t)N_NODES * DIM * 4);

    init_kernel<<<SCAN_B, 256, 0, stream>>>(deg, counts);
    hist_kernel<<<N_EDGES / 256, 256, 0, stream>>>(dst, ew, deg, counts);
    dinv_kernel<<<SCAN_B, 256, 0, stream>>>(deg, dinv);
    scan_a_kernel<<<SCAN_B, 256, 0, stream>>>(counts, bsum);
    scan_b_kernel<<<1, 256, 0, stream>>>(bsum, boff, rowptr);
    scan_c_kernel<<<SCAN_B, 256, 0, stream>>>(counts, boff, rowptr, cursor);
    fill_kernel<<<N_EDGES / 256, 256, 0, stream>>>(src, dst, ew, dinv, cursor, epack);
    convw_kernel<<<(5 * 65536) / 256, 256, 0, stream>>>(conv_w, post_w, Wt);

    const int GEMM_GRID = (N_NODES + 63) / 64;  // 782
    // layer 0 input: LN(emb) -> bf16
    ln_cast_kernel<<<N_NODES / 4, 256, 0, stream>>>(emb, ln_w, ln_b, Z16);
    const float* hin = emb;
    for (int l = 0; l < NLAYERS; ++l) {
        gemm_bf16_kernel<<<GEMM_GRID, 256, 0, stream>>>(Z16, Wt + (size_t)l * 65536, ZWb);
        int doLN = (l < NLAYERS - 1) ? 1 : 0;
        int writeH = (l < NLAYERS - 1) ? 1 : 0;
        const float* nlw = doLN ? (ln_w + (l + 1) * DIM) : nullptr;
        const float* nlb = doLN ? (ln_b + (l + 1) * DIM) : nullptr;
        agg_kernel<<<N_NODES / 4, 256, 0, stream>>>(ZWb, hin, H, conv_b + l * DIM,
                                                    rowptr, epack, dinv, nlw, nlb,
                                                    Z16, doLN, writeH);
        hin = H;
    }
    gemm_f32_kernel<<<GEMM_GRID, 256, 0, stream>>>(Z16, Wt + (size_t)4 * 65536, out, post_b);
}

// Round 4
// 736.443 us; speedup vs baseline: 1.5551x; 1.0111x over previous
//
#include <hip/hip_runtime.h>
#include <hip/hip_bf16.h>

#define N_NODES 50000
#define N_EDGES 800000
#define DIM     256
#define NLAYERS 4
#define EPS     1e-5f
#define SCAN_B  196   // ceil(50000/256)

typedef __bf16 bf16x8 __attribute__((ext_vector_type(8)));
typedef float  f32x4  __attribute__((ext_vector_type(4)));
typedef unsigned short u16x8 __attribute__((ext_vector_type(8)));

__device__ __forceinline__ unsigned short f2b(float f) {
    __hip_bfloat16 h = __float2bfloat16(f);
    return __builtin_bit_cast(unsigned short, h);
}
__device__ __forceinline__ float b2f(unsigned short u) {
    unsigned int v = ((unsigned int)u) << 16;
    return __builtin_bit_cast(float, v);
}
__device__ __forceinline__ float gelu_exact(float x) {
    return 0.5f * x * (1.0f + erff(x * 0.70710678118654752f));
}

// ---- setup kernels ------------------------------------------------------
__global__ __launch_bounds__(256) void init_kernel(float* deg, int* counts) {
    int i = blockIdx.x * 256 + threadIdx.x;
    if (i < N_NODES) { deg[i] = 1.0f; counts[i] = 0; }  // 1.0 = self-loop weight
}

__global__ __launch_bounds__(256) void hist_kernel(const int* __restrict__ dst,
                                                   const float* __restrict__ w,
                                                   float* deg, int* counts) {
    int e = blockIdx.x * 256 + threadIdx.x;
    if (e >= N_EDGES) return;
    int d = dst[e];
    atomicAdd(&deg[d], w[e]);
    atomicAdd(&counts[d], 1);
}

// block-sum of counts + dinv = rsqrt(deg) fused
__global__ __launch_bounds__(256) void scan_a_kernel(const int* __restrict__ counts,
                                                     const float* __restrict__ deg,
                                                     float* __restrict__ dinv,
                                                     int* __restrict__ bsum) {
    __shared__ int l[256];
    int i = blockIdx.x * 256 + threadIdx.x;
    if (i < N_NODES) dinv[i] = rsqrtf(deg[i]);  // deg >= 1 always (self-loop)
    l[threadIdx.x] = (i < N_NODES) ? counts[i] : 0;
    __syncthreads();
    for (int o = 128; o > 0; o >>= 1) {
        if (threadIdx.x < o) l[threadIdx.x] += l[threadIdx.x + o];
        __syncthreads();
    }
    if (threadIdx.x == 0) bsum[blockIdx.x] = l[0];
}

__global__ __launch_bounds__(256) void scan_b_kernel(const int* __restrict__ bsum,
                                                     int* __restrict__ boff,
                                                     int* __restrict__ rowptr) {
    __shared__ int l[256];
    int t = threadIdx.x;
    l[t] = (t < SCAN_B) ? bsum[t] : 0;
    __syncthreads();
    if (t == 0) {
        int run = 0;
        for (int j = 0; j < SCAN_B; ++j) { int v = l[j]; l[j] = run; run += v; }
        rowptr[N_NODES] = run;  // == N_EDGES
    }
    __syncthreads();
    boff[t] = l[t];
}

__global__ __launch_bounds__(256) void scan_c_kernel(const int* __restrict__ counts,
                                                     const int* __restrict__ boff,
                                                     int* __restrict__ rowptr,
                                                     int* __restrict__ cursor) {
    __shared__ int l[256];
    int i = blockIdx.x * 256 + threadIdx.x;
    l[threadIdx.x] = (i < N_NODES) ? counts[i] : 0;
    __syncthreads();
    if (threadIdx.x == 0) {
        int run = 0;
        for (int j = 0; j < 256; ++j) { int v = l[j]; l[j] = run; run += v; }
    }
    __syncthreads();
    if (i < N_NODES) {
        int rp = boff[blockIdx.x] + l[threadIdx.x];
        rowptr[i] = rp;
        cursor[i] = rp;
    }
}

__global__ __launch_bounds__(256) void fill_kernel(const int* __restrict__ src,
                                                   const int* __restrict__ dst,
                                                   const float* __restrict__ w,
                                                   const float* __restrict__ dinv,
                                                   int* cursor, int2* __restrict__ epack) {
    int e = blockIdx.x * 256 + threadIdx.x;
    if (e >= N_EDGES) return;
    int s = src[e], d = dst[e];
    int p = atomicAdd(&cursor[d], 1);
    float c = dinv[s] * w[e] * dinv[d];
    epack[p] = make_int2(s, __float_as_int(c));
}

// conv_w[l][k][n] (l<4) and post_w[k][n] (slot 4) -> Wt[l][n][k] bf16
__global__ __launch_bounds__(256) void convw_kernel(const float* __restrict__ conv_w,
                                                    const float* __restrict__ post_w,
                                                    unsigned short* __restrict__ Wt) {
    int idx = blockIdx.x * 256 + threadIdx.x;
    if (idx >= 5 * 65536) return;
    int m = idx >> 16;
    int r = idx & 65535;
    int n = r >> 8;
    int k = r & 255;
    float v = (m < 4) ? conv_w[m * 65536 + k * 256 + n] : post_w[k * 256 + n];
    Wt[idx] = f2b(v);
}

// ---- per-layer kernels --------------------------------------------------
// wave-per-row LayerNorm + bf16 cast (used once, on emb)
__global__ __launch_bounds__(256) void ln_cast_kernel(const float* __restrict__ H,
                                                      const float* __restrict__ lnw,
                                                      const float* __restrict__ lnb,
                                                      unsigned short* __restrict__ Z) {
    int row = blockIdx.x * 4 + (threadIdx.x >> 6);
    int lane = threadIdx.x & 63;
    const float4 x = *(const float4*)(H + (size_t)row * DIM + lane * 4);
    float s = x.x + x.y + x.z + x.w;
    for (int o = 32; o > 0; o >>= 1) s += __shfl_xor(s, o);
    float mu = s * (1.0f / DIM);
    float d0 = x.x - mu, d1 = x.y - mu, d2 = x.z - mu, d3 = x.w - mu;
    float v = d0 * d0 + d1 * d1 + d2 * d2 + d3 * d3;
    for (int o = 32; o > 0; o >>= 1) v += __shfl_xor(v, o);
    float rs = rsqrtf(v * (1.0f / DIM) + EPS);
    const float4 ww = *(const float4*)(lnw + lane * 4);
    const float4 bb = *(const float4*)(lnb + lane * 4);
    ushort4 o4;
    o4.x = f2b(d0 * rs * ww.x + bb.x);
    o4.y = f2b(d1 * rs * ww.y + bb.y);
    o4.z = f2b(d2 * rs * ww.z + bb.z);
    o4.w = f2b(d3 * rs * ww.w + bb.w);
    *(ushort4*)(Z + (size_t)row * DIM + lane * 4) = o4;
}

// ---- GEMM, transposed-operand form: weights are the MFMA A-operand
// (m=channel), node rows are the B-operand (n=node). C/D: col(lane&15)=node,
// row(q*4+r)=channel -> each lane holds 4 CONSECUTIVE channels of one node:
// direct vector stores, no LDS transpose.
// Block = 4 waves; block tile 64 nodes x 256 chans; wave w: 64 nodes x chans
// [64w, 64w+64) as 4x4 MFMA tiles. MODE 0: bf16 out. MODE 1: fp32 out + bias.
template <int MODE>
__device__ __forceinline__ void gemm_body(const unsigned short* __restrict__ A,
                                          const unsigned short* __restrict__ Bt,
                                          void* __restrict__ Cout,
                                          const float* __restrict__ bias) {
    int tid = threadIdx.x;
    int wave = tid >> 6;
    int lane = tid & 63;
    int q = lane >> 4;       // 0..3
    int c16 = lane & 15;
    int mbase = blockIdx.x * 64;   // node base
    int cbase = wave * 64;         // channel base

    const unsigned short* aptr[4];   // node rows (B-operand source)
    #pragma unroll
    for (int nt = 0; nt < 4; ++nt) {
        int row = mbase + nt * 16 + c16;
        if (row >= N_NODES) row = N_NODES - 1;   // clamp; stores guarded
        aptr[nt] = A + (size_t)row * DIM;
    }
    const unsigned short* wptr[4];   // weight rows Wt[chan][k] (A-operand source)
    #pragma unroll
    for (int ct = 0; ct < 4; ++ct)
        wptr[ct] = Bt + (size_t)(cbase + ct * 16 + c16) * DIM;

    f32x4 acc[4][4] = {};   // [node-subtile][chan-subtile]
    #pragma unroll 1
    for (int k0 = 0; k0 < DIM; k0 += 32) {
        bf16x8 nf[4], wf[4];
        #pragma unroll
        for (int nt = 0; nt < 4; ++nt)
            nf[nt] = __builtin_bit_cast(bf16x8, *(const u16x8*)(aptr[nt] + k0 + q * 8));
        #pragma unroll
        for (int ct = 0; ct < 4; ++ct)
            wf[ct] = __builtin_bit_cast(bf16x8, *(const u16x8*)(wptr[ct] + k0 + q * 8));
        #pragma unroll
        for (int nt = 0; nt < 4; ++nt)
            #pragma unroll
            for (int ct = 0; ct < 4; ++ct)
                acc[nt][ct] = __builtin_amdgcn_mfma_f32_16x16x32_bf16(wf[ct], nf[nt], acc[nt][ct], 0, 0, 0);
    }

    float4 bb[4];
    if (MODE == 1) {
        #pragma unroll
        for (int ct = 0; ct < 4; ++ct)
            bb[ct] = *(const float4*)(bias + cbase + ct * 16 + q * 4);
    }
    #pragma unroll
    for (int nt = 0; nt < 4; ++nt) {
        int node = mbase + nt * 16 + c16;
        if (node >= N_NODES) continue;
        #pragma unroll
        for (int ct = 0; ct < 4; ++ct) {
            int chan = cbase + ct * 16 + q * 4;
            if (MODE == 0) {
                unsigned short* C = (unsigned short*)Cout;
                ushort4 o4;
                o4.x = f2b(acc[nt][ct][0]);
                o4.y = f2b(acc[nt][ct][1]);
                o4.z = f2b(acc[nt][ct][2]);
                o4.w = f2b(acc[nt][ct][3]);
                *(ushort4*)(C + (size_t)node * DIM + chan) = o4;
            } else {
                float* C = (float*)Cout;
                float4 o;
                o.x = acc[nt][ct][0] + bb[ct].x;
                o.y = acc[nt][ct][1] + bb[ct].y;
                o.z = acc[nt][ct][2] + bb[ct].z;
                o.w = acc[nt][ct][3] + bb[ct].w;
                *(float4*)(C + (size_t)node * DIM + chan) = o;
            }
        }
    }
}

__global__ __launch_bounds__(256) void gemm_bf16_kernel(const unsigned short* __restrict__ A,
                                                        const unsigned short* __restrict__ Bt,
                                                        unsigned short* __restrict__ C) {
    gemm_body<0>(A, Bt, C, nullptr);
}

__global__ __launch_bounds__(256) void gemm_f32_kernel(const unsigned short* __restrict__ A,
                                                       const unsigned short* __restrict__ Bt,
                                                       float* __restrict__ C,
                                                       const float* __restrict__ bias) {
    gemm_body<1>(A, Bt, C, bias);
}

// wave-per-node CSR aggregation: half-wave (32 lanes x 16B) per edge-row,
// 4 edges per half in flight (8 per wave). Fused bias + exact GELU +
// residual + next-layer LN/cast -> Z16 bf16.
__global__ __launch_bounds__(256) void agg_kernel(const unsigned short* __restrict__ ZW,
                                                  const float* __restrict__ Hin,
                                                  float* __restrict__ Hout,
                                                  const float* __restrict__ bias,
                                                  const int* __restrict__ rowptr,
                                                  const int2* __restrict__ epack,
                                                  const float* __restrict__ dinv,
                                                  const float* __restrict__ lnw,
                                                  const float* __restrict__ lnb,
                                                  unsigned short* __restrict__ Zout,
                                                  int doLN, int writeH) {
    int node = blockIdx.x * 4 + (threadIdx.x >> 6);
    int lane = threadIdx.x & 63;
    int g = lane >> 5;          // half id
    int col0 = (lane & 31) * 8; // 8 contiguous cols per lane

    float di = dinv[node];
    float scg = (g == 0) ? di * di : 0.0f;   // self-loop only in half 0
    const u16x8 zs = *(const u16x8*)(ZW + (size_t)node * DIM + col0);
    float a[8];
    #pragma unroll
    for (int j = 0; j < 8; ++j) a[j] = scg * b2f(zs[j]);

    int e0 = rowptr[node], e1 = rowptr[node + 1];
    for (int e = e0; e < e1; e += 8) {
        int base = e + 4 * g;
        int i0 = base,     v0ok = (i0 < e1); if (!v0ok) i0 = e0;
        int i1 = base + 1, v1ok = (i1 < e1); if (!v1ok) i1 = e0;
        int i2 = base + 2, v2ok = (i2 < e1); if (!v2ok) i2 = e0;
        int i3 = base + 3, v3ok = (i3 < e1); if (!v3ok) i3 = e0;
        int2 p0 = epack[i0];
        int2 p1 = epack[i1];
        int2 p2 = epack[i2];
        int2 p3 = epack[i3];
        const u16x8 v0 = *(const u16x8*)(ZW + (size_t)p0.x * DIM + col0);
        const u16x8 v1 = *(const u16x8*)(ZW + (size_t)p1.x * DIM + col0);
        const u16x8 v2 = *(const u16x8*)(ZW + (size_t)p2.x * DIM + col0);
        const u16x8 v3 = *(const u16x8*)(ZW + (size_t)p3.x * DIM + col0);
        float c0 = v0ok ? __int_as_float(p0.y) : 0.0f;
        float c1 = v1ok ? __int_as_float(p1.y) : 0.0f;
        float c2 = v2ok ? __int_as_float(p2.y) : 0.0f;
        float c3 = v3ok ? __int_as_float(p3.y) : 0.0f;
        #pragma unroll
        for (int j = 0; j < 8; ++j) {
            a[j] += c0 * b2f(v0[j]);
            a[j] += c1 * b2f(v1[j]);
            a[j] += c2 * b2f(v2[j]);
            a[j] += c3 * b2f(v3[j]);
        }
    }
    // combine the two halves
    #pragma unroll
    for (int j = 0; j < 8; ++j) a[j] += __shfl_xor(a[j], 32);

    const float4 bb0 = *(const float4*)(bias + col0);
    const float4 bb1 = *(const float4*)(bias + col0 + 4);
    const float4 h0 = *(const float4*)(Hin + (size_t)node * DIM + col0);
    const float4 h1 = *(const float4*)(Hin + (size_t)node * DIM + col0 + 4);
    float o[8];
    o[0] = h0.x + gelu_exact(a[0] + bb0.x);
    o[1] = h0.y + gelu_exact(a[1] + bb0.y);
    o[2] = h0.z + gelu_exact(a[2] + bb0.z);
    o[3] = h0.w + gelu_exact(a[3] + bb0.w);
    o[4] = h1.x + gelu_exact(a[4] + bb1.x);
    o[5] = h1.y + gelu_exact(a[5] + bb1.y);
    o[6] = h1.z + gelu_exact(a[6] + bb1.z);
    o[7] = h1.w + gelu_exact(a[7] + bb1.w);

    if (writeH && g == 0) {
        float4 w0, w1;
        w0.x = o[0]; w0.y = o[1]; w0.z = o[2]; w0.w = o[3];
        w1.x = o[4]; w1.y = o[5]; w1.z = o[6]; w1.w = o[7];
        *(float4*)(Hout + (size_t)node * DIM + col0) = w0;
        *(float4*)(Hout + (size_t)node * DIM + col0 + 4) = w1;
    }

    float y[8];
    #pragma unroll
    for (int j = 0; j < 8; ++j) y[j] = o[j];
    if (doLN) {
        float s = 0.0f;
        #pragma unroll
        for (int j = 0; j < 8; ++j) s += o[j];
        for (int off = 16; off > 0; off >>= 1) s += __shfl_xor(s, off);
        float mu = s * (1.0f / DIM);
        float v = 0.0f;
        float d[8];
        #pragma unroll
        for (int j = 0; j < 8; ++j) { d[j] = o[j] - mu; v += d[j] * d[j]; }
        for (int off = 16; off > 0; off >>= 1) v += __shfl_xor(v, off);
        float rs = rsqrtf(v * (1.0f / DIM) + EPS);
        const float4 ww0 = *(const float4*)(lnw + col0);
        const float4 ww1 = *(const float4*)(lnw + col0 + 4);
        const float4 lb0 = *(const float4*)(lnb + col0);
        const float4 lb1 = *(const float4*)(lnb + col0 + 4);
        y[0] = d[0] * rs * ww0.x + lb0.x;
        y[1] = d[1] * rs * ww0.y + lb0.y;
        y[2] = d[2] * rs * ww0.z + lb0.z;
        y[3] = d[3] * rs * ww0.w + lb0.w;
        y[4] = d[4] * rs * ww1.x + lb1.x;
        y[5] = d[5] * rs * ww1.y + lb1.y;
        y[6] = d[6] * rs * ww1.z + lb1.z;
        y[7] = d[7] * rs * ww1.w + lb1.w;
    }
    if (g == 0) {
        u16x8 z;
        #pragma unroll
        for (int j = 0; j < 8; ++j) z[j] = f2b(y[j]);
        *(u16x8*)(Zout + (size_t)node * DIM + col0) = z;
    }
}

// ---- launch -------------------------------------------------------------
extern "C" void kernel_launch(void* const* d_in, const int* in_sizes, int n_in,
                              void* d_out, int out_size, void* d_ws, size_t ws_size,
                              hipStream_t stream) {
    const int*   ei     = (const int*)d_in[1];
    const int*   src    = ei;
    const int*   dst    = ei + N_EDGES;
    const float* ew     = (const float*)d_in[2];
    const float* emb    = (const float*)d_in[3];
    const float* ln_w   = (const float*)d_in[4];
    const float* ln_b   = (const float*)d_in[5];
    const float* conv_w = (const float*)d_in[6];
    const float* conv_b = (const float*)d_in[7];
    const float* post_w = (const float*)d_in[8];
    const float* post_b = (const float*)d_in[9];
    float* out = (float*)d_out;

    char* w = (char*)d_ws;
    size_t off = 0;
    auto alloc = [&](size_t bytes) -> char* {
        char* p = w + off;
        off += (bytes + 255) & ~(size_t)255;
        return p;
    };
    float* deg    = (float*)alloc((size_t)N_NODES * 4);
    float* dinv   = (float*)alloc((size_t)N_NODES * 4);
    int*   counts = (int*)alloc((size_t)N_NODES * 4);
    int*   rowptr = (int*)alloc((size_t)(N_NODES + 1) * 4);
    int*   cursor = (int*)alloc((size_t)N_NODES * 4);
    int*   bsum   = (int*)alloc(256 * 4);
    int*   boff   = (int*)alloc(256 * 4);
    int2*  epack  = (int2*)alloc((size_t)(N_EDGES + 8) * 8);  // +8: tail-read slack
    unsigned short* Wt  = (unsigned short*)alloc((size_t)5 * 65536 * 2);
    unsigned short* Z16 = (unsigned short*)alloc((size_t)N_NODES * DIM * 2);
    unsigned short* ZWb = (unsigned short*)alloc((size_t)N_NODES * DIM * 2);
    float* H  = (float*)alloc((size_t)N_NODES * DIM * 4);

    init_kernel<<<SCAN_B, 256, 0, stream>>>(deg, counts);
    hist_kernel<<<N_EDGES / 256, 256, 0, stream>>>(dst, ew, deg, counts);
    scan_a_kernel<<<SCAN_B, 256, 0, stream>>>(counts, deg, dinv, bsum);
    scan_b_kernel<<<1, 256, 0, stream>>>(bsum, boff, rowptr);
    scan_c_kernel<<<SCAN_B, 256, 0, stream>>>(counts, boff, rowptr, cursor);
    fill_kernel<<<N_EDGES / 256, 256, 0, stream>>>(src, dst, ew, dinv, cursor, epack);
    convw_kernel<<<(5 * 65536) / 256, 256, 0, stream>>>(conv_w, post_w, Wt);

    const int GEMM_GRID = (N_NODES + 63) / 64;  // 782
    // layer 0 input: LN(emb) -> bf16
    ln_cast_kernel<<<N_NODES / 4, 256, 0, stream>>>(emb, ln_w, ln_b, Z16);
    const float* hin = emb;
    for (int l = 0; l < NLAYERS; ++l) {
        gemm_bf16_kernel<<<GEMM_GRID, 256, 0, stream>>>(Z16, Wt + (size_t)l * 65536, ZWb);
        int doLN = (l < NLAYERS - 1) ? 1 : 0;
        int writeH = (l < NLAYERS - 1) ? 1 : 0;
        const float* nlw = doLN ? (ln_w + (l + 1) * DIM) : nullptr;
        const float* nlb = doLN ? (ln_b + (l + 1) * DIM) : nullptr;
        agg_kernel<<<N_NODES / 4, 256, 0, stream>>>(ZWb, hin, H, conv_b + l * DIM,
                                                    rowptr, epack, dinv, nlw, nlb,
                                                    Z16, doLN, writeH);
        hin = H;
    }
    gemm_f32_kernel<<<GEMM_GRID, 256, 0, stream>>>(Z16, Wt + (size_t)4 * 65536, out, post_b);
}

// Round 5
// 682.196 us; speedup vs baseline: 1.6787x; 1.0795x over previous
//
#include <hip/hip_runtime.h>
#include <hip/hip_bf16.h>

#define N_NODES 50000
#define N_EDGES 800000
#define DIM     256
#define NLAYERS 4
#define EPS     1e-5f
#define SCAN_B  196   // ceil(50000/256)
#define MASK40  ((1ULL << 40) - 1)
#define EPACK_CAP (N_EDGES + 7 * N_NODES + 16)   // padded CSR capacity

typedef __bf16 bf16x8 __attribute__((ext_vector_type(8)));
typedef float  f32x4  __attribute__((ext_vector_type(4)));
typedef unsigned short u16x8 __attribute__((ext_vector_type(8)));

__device__ __forceinline__ unsigned short f2b(float f) {
    __hip_bfloat16 h = __float2bfloat16(f);
    return __builtin_bit_cast(unsigned short, h);
}
__device__ __forceinline__ float b2f(unsigned short u) {
    unsigned int v = ((unsigned int)u) << 16;
    return __builtin_bit_cast(float, v);
}
__device__ __forceinline__ float gelu_exact(float x) {
    return 0.5f * x * (1.0f + erff(x * 0.70710678118654752f));
}

// ---- setup kernels ------------------------------------------------------
// One packed u64 atomic per edge: bits [40,64) = count, [0,40) = sum(w)*2^32.
// Returned old value's count field = this edge's rank within its dst row.
__global__ __launch_bounds__(256) void hist_kernel(const int* __restrict__ dst,
                                                   const float* __restrict__ w,
                                                   unsigned long long* __restrict__ cnt64,
                                                   int* __restrict__ rank) {
    int e = blockIdx.x * 256 + threadIdx.x;
    if (e >= N_EDGES) return;
    int d = dst[e];
    unsigned long long wfix = (unsigned long long)(w[e] * 4294967296.0f);
    unsigned long long old = atomicAdd(&cnt64[d], (1ULL << 40) | wfix);
    rank[e] = (int)(old >> 40);
}

// dinv = rsqrt(1 + sum(w)) ; block-sum of padded counts
__global__ __launch_bounds__(256) void scan_a_kernel(const unsigned long long* __restrict__ cnt64,
                                                     float* __restrict__ dinv,
                                                     int* __restrict__ bsum) {
    __shared__ int l[256];
    int i = blockIdx.x * 256 + threadIdx.x;
    int pc = 0;
    if (i < N_NODES) {
        unsigned long long v = cnt64[i];
        int cnt = (int)(v >> 40);
        float sw = (float)(v & MASK40) * 2.3283064365386963e-10f;  // *2^-32
        dinv[i] = rsqrtf(1.0f + sw);
        pc = (cnt + 7) & ~7;
    }
    l[threadIdx.x] = pc;
    __syncthreads();
    for (int o = 128; o > 0; o >>= 1) {
        if (threadIdx.x < o) l[threadIdx.x] += l[threadIdx.x + o];
        __syncthreads();
    }
    if (threadIdx.x == 0) bsum[blockIdx.x] = l[0];
}

__global__ __launch_bounds__(256) void scan_b_kernel(const int* __restrict__ bsum,
                                                     int* __restrict__ boff,
                                                     int* __restrict__ rowptr) {
    __shared__ int l[256];
    int t = threadIdx.x;
    l[t] = (t < SCAN_B) ? bsum[t] : 0;
    __syncthreads();
    if (t == 0) {
        int run = 0;
        for (int j = 0; j < SCAN_B; ++j) { int v = l[j]; l[j] = run; run += v; }
        rowptr[N_NODES] = run;  // total padded entries
    }
    __syncthreads();
    boff[t] = l[t];
}

__global__ __launch_bounds__(256) void scan_c_kernel(const unsigned long long* __restrict__ cnt64,
                                                     const int* __restrict__ boff,
                                                     int* __restrict__ rowptr) {
    __shared__ int l[256];
    int i = blockIdx.x * 256 + threadIdx.x;
    int pc = 0;
    if (i < N_NODES) {
        int cnt = (int)(cnt64[i] >> 40);
        pc = (cnt + 7) & ~7;
    }
    l[threadIdx.x] = pc;
    __syncthreads();
    if (threadIdx.x == 0) {
        int run = 0;
        for (int j = 0; j < 256; ++j) { int v = l[j]; l[j] = run; run += v; }
    }
    __syncthreads();
    if (i < N_NODES) rowptr[i] = boff[blockIdx.x] + l[threadIdx.x];
}

// No atomics: position = rowptr[dst] + rank.  epack.x = src byte-offset (src*512).
__global__ __launch_bounds__(256) void fill_kernel(const int* __restrict__ src,
                                                   const int* __restrict__ dst,
                                                   const float* __restrict__ w,
                                                   const float* __restrict__ dinv,
                                                   const int* __restrict__ rowptr,
                                                   const int* __restrict__ rank,
                                                   int2* __restrict__ epack) {
    int e = blockIdx.x * 256 + threadIdx.x;
    if (e >= N_EDGES) return;
    int s = src[e], d = dst[e];
    float c = dinv[s] * w[e] * dinv[d];
    int p = rowptr[d] + rank[e];
    epack[p] = make_int2(s << 9, __float_as_int(c));
}

// conv_w[l][k][n] (l<4) and post_w[k][n] (slot 4) -> Wt[l][n][k] bf16
__global__ __launch_bounds__(256) void convw_kernel(const float* __restrict__ conv_w,
                                                    const float* __restrict__ post_w,
                                                    unsigned short* __restrict__ Wt) {
    int idx = blockIdx.x * 256 + threadIdx.x;
    if (idx >= 5 * 65536) return;
    int m = idx >> 16;
    int r = idx & 65535;
    int n = r >> 8;
    int k = r & 255;
    float v = (m < 4) ? conv_w[m * 65536 + k * 256 + n] : post_w[k * 256 + n];
    Wt[idx] = f2b(v);
}

// ---- per-layer kernels --------------------------------------------------
// wave-per-row LayerNorm + bf16 cast (used once, on emb)
__global__ __launch_bounds__(256) void ln_cast_kernel(const float* __restrict__ H,
                                                      const float* __restrict__ lnw,
                                                      const float* __restrict__ lnb,
                                                      unsigned short* __restrict__ Z) {
    int row = blockIdx.x * 4 + (threadIdx.x >> 6);
    int lane = threadIdx.x & 63;
    const float4 x = *(const float4*)(H + (size_t)row * DIM + lane * 4);
    float s = x.x + x.y + x.z + x.w;
    for (int o = 32; o > 0; o >>= 1) s += __shfl_xor(s, o);
    float mu = s * (1.0f / DIM);
    float d0 = x.x - mu, d1 = x.y - mu, d2 = x.z - mu, d3 = x.w - mu;
    float v = d0 * d0 + d1 * d1 + d2 * d2 + d3 * d3;
    for (int o = 32; o > 0; o >>= 1) v += __shfl_xor(v, o);
    float rs = rsqrtf(v * (1.0f / DIM) + EPS);
    const float4 ww = *(const float4*)(lnw + lane * 4);
    const float4 bb = *(const float4*)(lnb + lane * 4);
    ushort4 o4;
    o4.x = f2b(d0 * rs * ww.x + bb.x);
    o4.y = f2b(d1 * rs * ww.y + bb.y);
    o4.z = f2b(d2 * rs * ww.z + bb.z);
    o4.w = f2b(d3 * rs * ww.w + bb.w);
    *(ushort4*)(Z + (size_t)row * DIM + lane * 4) = o4;
}

// ---- GEMM, transposed-operand form (round-4 structure, unchanged) -------
template <int MODE>
__device__ __forceinline__ void gemm_body(const unsigned short* __restrict__ A,
                                          const unsigned short* __restrict__ Bt,
                                          void* __restrict__ Cout,
                                          const float* __restrict__ bias) {
    int tid = threadIdx.x;
    int wave = tid >> 6;
    int lane = tid & 63;
    int q = lane >> 4;
    int c16 = lane & 15;
    int mbase = blockIdx.x * 64;   // node base
    int cbase = wave * 64;         // channel base

    const unsigned short* aptr[4];
    #pragma unroll
    for (int nt = 0; nt < 4; ++nt) {
        int row = mbase + nt * 16 + c16;
        if (row >= N_NODES) row = N_NODES - 1;
        aptr[nt] = A + (size_t)row * DIM;
    }
    const unsigned short* wptr[4];
    #pragma unroll
    for (int ct = 0; ct < 4; ++ct)
        wptr[ct] = Bt + (size_t)(cbase + ct * 16 + c16) * DIM;

    f32x4 acc[4][4] = {};
    #pragma unroll 1
    for (int k0 = 0; k0 < DIM; k0 += 32) {
        bf16x8 nf[4], wf[4];
        #pragma unroll
        for (int nt = 0; nt < 4; ++nt)
            nf[nt] = __builtin_bit_cast(bf16x8, *(const u16x8*)(aptr[nt] + k0 + q * 8));
        #pragma unroll
        for (int ct = 0; ct < 4; ++ct)
            wf[ct] = __builtin_bit_cast(bf16x8, *(const u16x8*)(wptr[ct] + k0 + q * 8));
        #pragma unroll
        for (int nt = 0; nt < 4; ++nt)
            #pragma unroll
            for (int ct = 0; ct < 4; ++ct)
                acc[nt][ct] = __builtin_amdgcn_mfma_f32_16x16x32_bf16(wf[ct], nf[nt], acc[nt][ct], 0, 0, 0);
    }

    float4 bb[4];
    if (MODE == 1) {
        #pragma unroll
        for (int ct = 0; ct < 4; ++ct)
            bb[ct] = *(const float4*)(bias + cbase + ct * 16 + q * 4);
    }
    #pragma unroll
    for (int nt = 0; nt < 4; ++nt) {
        int node = mbase + nt * 16 + c16;
        if (node >= N_NODES) continue;
        #pragma unroll
        for (int ct = 0; ct < 4; ++ct) {
            int chan = cbase + ct * 16 + q * 4;
            if (MODE == 0) {
                unsigned short* C = (unsigned short*)Cout;
                ushort4 o4;
                o4.x = f2b(acc[nt][ct][0]);
                o4.y = f2b(acc[nt][ct][1]);
                o4.z = f2b(acc[nt][ct][2]);
                o4.w = f2b(acc[nt][ct][3]);
                *(ushort4*)(C + (size_t)node * DIM + chan) = o4;
            } else {
                float* C = (float*)Cout;
                float4 o;
                o.x = acc[nt][ct][0] + bb[ct].x;
                o.y = acc[nt][ct][1] + bb[ct].y;
                o.z = acc[nt][ct][2] + bb[ct].z;
                o.w = acc[nt][ct][3] + bb[ct].w;
                *(float4*)(C + (size_t)node * DIM + chan) = o;
            }
        }
    }
}

__global__ __launch_bounds__(256) void gemm_bf16_kernel(const unsigned short* __restrict__ A,
                                                        const unsigned short* __restrict__ Bt,
                                                        unsigned short* __restrict__ C) {
    gemm_body<0>(A, Bt, C, nullptr);
}

__global__ __launch_bounds__(256) void gemm_f32_kernel(const unsigned short* __restrict__ A,
                                                       const unsigned short* __restrict__ Bt,
                                                       float* __restrict__ C,
                                                       const float* __restrict__ bias) {
    gemm_body<1>(A, Bt, C, bias);
}

// wave-per-node CSR aggregation over PADDED rows (pad entries: off=0, coef=0).
// Half-wave (32 lanes x 16B) per edge, 4 edges per half in flight, no bounds
// checks, 32-bit pre-shifted byte offsets. Fused bias + exact GELU + residual
// + next-layer LN/cast -> Z16 bf16.
__global__ __launch_bounds__(256) void agg_kernel(const char* __restrict__ ZW,
                                                  const float* __restrict__ Hin,
                                                  float* __restrict__ Hout,
                                                  const float* __restrict__ bias,
                                                  const int* __restrict__ rowptr,
                                                  const int2* __restrict__ epack,
                                                  const float* __restrict__ dinv,
                                                  const float* __restrict__ lnw,
                                                  const float* __restrict__ lnb,
                                                  unsigned short* __restrict__ Zout,
                                                  int doLN, int writeH) {
    int node = blockIdx.x * 4 + (threadIdx.x >> 6);
    int lane = threadIdx.x & 63;
    int g = lane >> 5;            // half id
    int colB = (lane & 31) * 16;  // byte offset of this lane's 8 bf16

    float di = dinv[node];
    float scg = (g == 0) ? di * di : 0.0f;   // self-loop only in half 0
    const u16x8 zs = *(const u16x8*)(ZW + node * 512 + colB);
    float a[8];
    #pragma unroll
    for (int j = 0; j < 8; ++j) a[j] = scg * b2f(zs[j]);

    int e0 = rowptr[node], e1 = rowptr[node + 1];
    for (int e = e0; e < e1; e += 8) {
        const int2* pp = epack + e + 4 * g;
        const int4 q0 = *(const int4*)pp;        // edges 0,1: (off,coef)x2
        const int4 q1 = *(const int4*)(pp + 2);  // edges 2,3
        const u16x8 v0 = *(const u16x8*)(ZW + q0.x + colB);
        const u16x8 v1 = *(const u16x8*)(ZW + q0.z + colB);
        const u16x8 v2 = *(const u16x8*)(ZW + q1.x + colB);
        const u16x8 v3 = *(const u16x8*)(ZW + q1.z + colB);
        float c0 = __int_as_float(q0.y);
        float c1 = __int_as_float(q0.w);
        float c2 = __int_as_float(q1.y);
        float c3 = __int_as_float(q1.w);
        #pragma unroll
        for (int j = 0; j < 8; ++j) {
            a[j] += c0 * b2f(v0[j]);
            a[j] += c1 * b2f(v1[j]);
            a[j] += c2 * b2f(v2[j]);
            a[j] += c3 * b2f(v3[j]);
        }
    }
    // combine the two halves
    #pragma unroll
    for (int j = 0; j < 8; ++j) a[j] += __shfl_xor(a[j], 32);

    int col0 = (lane & 31) * 8;
    const float4 bb0 = *(const float4*)(bias + col0);
    const float4 bb1 = *(const float4*)(bias + col0 + 4);
    const float4 h0 = *(const float4*)(Hin + (size_t)node * DIM + col0);
    const float4 h1 = *(const float4*)(Hin + (size_t)node * DIM + col0 + 4);
    float o[8];
    o[0] = h0.x + gelu_exact(a[0] + bb0.x);
    o[1] = h0.y + gelu_exact(a[1] + bb0.y);
    o[2] = h0.z + gelu_exact(a[2] + bb0.z);
    o[3] = h0.w + gelu_exact(a[3] + bb0.w);
    o[4] = h1.x + gelu_exact(a[4] + bb1.x);
    o[5] = h1.y + gelu_exact(a[5] + bb1.y);
    o[6] = h1.z + gelu_exact(a[6] + bb1.z);
    o[7] = h1.w + gelu_exact(a[7] + bb1.w);

    if (writeH && g == 0) {
        float4 w0, w1;
        w0.x = o[0]; w0.y = o[1]; w0.z = o[2]; w0.w = o[3];
        w1.x = o[4]; w1.y = o[5]; w1.z = o[6]; w1.w = o[7];
        *(float4*)(Hout + (size_t)node * DIM + col0) = w0;
        *(float4*)(Hout + (size_t)node * DIM + col0 + 4) = w1;
    }

    float y[8];
    #pragma unroll
    for (int j = 0; j < 8; ++j) y[j] = o[j];
    if (doLN) {
        float s = 0.0f;
        #pragma unroll
        for (int j = 0; j < 8; ++j) s += o[j];
        for (int off = 16; off > 0; off >>= 1) s += __shfl_xor(s, off);
        float mu = s * (1.0f / DIM);
        float v = 0.0f;
        float d[8];
        #pragma unroll
        for (int j = 0; j < 8; ++j) { d[j] = o[j] - mu; v += d[j] * d[j]; }
        for (int off = 16; off > 0; off >>= 1) v += __shfl_xor(v, off);
        float rs = rsqrtf(v * (1.0f / DIM) + EPS);
        const float4 ww0 = *(const float4*)(lnw + col0);
        const float4 ww1 = *(const float4*)(lnw + col0 + 4);
        const float4 lb0 = *(const float4*)(lnb + col0);
        const float4 lb1 = *(const float4*)(lnb + col0 + 4);
        y[0] = d[0] * rs * ww0.x + lb0.x;
        y[1] = d[1] * rs * ww0.y + lb0.y;
        y[2] = d[2] * rs * ww0.z + lb0.z;
        y[3] = d[3] * rs * ww0.w + lb0.w;
        y[4] = d[4] * rs * ww1.x + lb1.x;
        y[5] = d[5] * rs * ww1.y + lb1.y;
        y[6] = d[6] * rs * ww1.z + lb1.z;
        y[7] = d[7] * rs * ww1.w + lb1.w;
    }
    if (g == 0) {
        u16x8 z;
        #pragma unroll
        for (int j = 0; j < 8; ++j) z[j] = f2b(y[j]);
        *(u16x8*)(Zout + (size_t)node * DIM + col0) = z;
    }
}

// ---- launch -------------------------------------------------------------
extern "C" void kernel_launch(void* const* d_in, const int* in_sizes, int n_in,
                              void* d_out, int out_size, void* d_ws, size_t ws_size,
                              hipStream_t stream) {
    const int*   ei     = (const int*)d_in[1];
    const int*   src    = ei;
    const int*   dst    = ei + N_EDGES;
    const float* ew     = (const float*)d_in[2];
    const float* emb    = (const float*)d_in[3];
    const float* ln_w   = (const float*)d_in[4];
    const float* ln_b   = (const float*)d_in[5];
    const float* conv_w = (const float*)d_in[6];
    const float* conv_b = (const float*)d_in[7];
    const float* post_w = (const float*)d_in[8];
    const float* post_b = (const float*)d_in[9];
    float* out = (float*)d_out;

    char* w = (char*)d_ws;
    size_t off = 0;
    auto alloc = [&](size_t bytes) -> char* {
        char* p = w + off;
        off += (bytes + 255) & ~(size_t)255;
        return p;
    };
    unsigned long long* cnt64 = (unsigned long long*)alloc((size_t)N_NODES * 8);
    float* dinv   = (float*)alloc((size_t)N_NODES * 4);
    int*   rank   = (int*)alloc((size_t)N_EDGES * 4);
    int*   rowptr = (int*)alloc((size_t)(N_NODES + 1) * 4);
    int*   bsum   = (int*)alloc(256 * 4);
    int*   boff   = (int*)alloc(256 * 4);
    int2*  epack  = (int2*)alloc((size_t)EPACK_CAP * 8);
    unsigned short* Wt  = (unsigned short*)alloc((size_t)5 * 65536 * 2);
    unsigned short* Z16 = (unsigned short*)alloc((size_t)N_NODES * DIM * 2);
    unsigned short* ZWb = (unsigned short*)alloc((size_t)N_NODES * DIM * 2);
    float* H  = (float*)alloc((size_t)N_NODES * DIM * 4);

    hipMemsetAsync(cnt64, 0, (size_t)N_NODES * 8, stream);
    hipMemsetAsync(epack, 0, (size_t)EPACK_CAP * 8, stream);
    hist_kernel<<<N_EDGES / 256, 256, 0, stream>>>(dst, ew, cnt64, rank);
    scan_a_kernel<<<SCAN_B, 256, 0, stream>>>(cnt64, dinv, bsum);
    scan_b_kernel<<<1, 256, 0, stream>>>(bsum, boff, rowptr);
    scan_c_kernel<<<SCAN_B, 256, 0, stream>>>(cnt64, boff, rowptr);
    fill_kernel<<<N_EDGES / 256, 256, 0, stream>>>(src, dst, ew, dinv, rowptr, rank, epack);
    convw_kernel<<<(5 * 65536) / 256, 256, 0, stream>>>(conv_w, post_w, Wt);

    const int GEMM_GRID = (N_NODES + 63) / 64;  // 782
    ln_cast_kernel<<<N_NODES / 4, 256, 0, stream>>>(emb, ln_w, ln_b, Z16);
    const float* hin = emb;
    for (int l = 0; l < NLAYERS; ++l) {
        gemm_bf16_kernel<<<GEMM_GRID, 256, 0, stream>>>(Z16, Wt + (size_t)l * 65536, ZWb);
        int doLN = (l < NLAYERS - 1) ? 1 : 0;
        int writeH = (l < NLAYERS - 1) ? 1 : 0;
        const float* nlw = doLN ? (ln_w + (l + 1) * DIM) : nullptr;
        const float* nlb = doLN ? (ln_b + (l + 1) * DIM) : nullptr;
        agg_kernel<<<N_NODES / 4, 256, 0, stream>>>((const char*)ZWb, hin, H, conv_b + l * DIM,
                                                    rowptr, epack, dinv, nlw, nlb,
                                                    Z16, doLN, writeH);
        hin = H;
    }
    gemm_f32_kernel<<<GEMM_GRID, 256, 0, stream>>>(Z16, Wt + (size_t)4 * 65536, out, post_b);
}